// Round 6
// baseline (11270.915 us; speedup 1.0000x reference)
//
#include <hip/hip_runtime.h>

#define T_STEPS 4096
#define RSIZE   2048
#define N_IN    8
#define N_OUT   4
#define NWG     256                  // 256 WGs x 4 waves = 1024 waves x 2 rows = 2048
#define NT      256
#define LIN_STRIDE  (RSIZE + N_IN)   // 2056 — readout weight row stride
#define SENTINEL    0x7FC00000u      // qNaN bits; recurrence never produces it

typedef float v4 __attribute__((ext_vector_type(4)));

// d_ws: states [T][R] float. Row 0 zeros, rows 1.. sentinel. Data IS the flag.

__global__ __launch_bounds__(256) void init_kernel(v4* __restrict__ states4) {
    int idx = blockIdx.x * 256 + threadIdx.x;        // 0 .. T*R/4-1
    const float s = __uint_as_float(SENTINEL);
    v4 v = (idx < RSIZE / 4) ? (v4){0.f, 0.f, 0.f, 0.f} : (v4){s, s, s, s};
    states4[idx] = v;
}

__device__ __forceinline__ float dot4(v4 a, v4 b) {
    float s = a.x * b.x;
    s = fmaf(a.y, b.y, s);
    s = fmaf(a.z, b.z, s);
    s = fmaf(a.w, b.w, s);
    return s;
}

__global__ __launch_bounds__(NT, 1) void reservoir_kernel(
    const float* __restrict__ W,        // [R][R]
    const float* __restrict__ Win,      // [R][8]
    const float* __restrict__ Wfb,      // [R][4]
    const float* __restrict__ inputs,   // [T][8]
    const float* __restrict__ outputs,  // [T][4]
    const float* __restrict__ noise,    // [T][R]
    float* __restrict__ states)         // [T][R]
{
    const int g    = blockIdx.x;
    const int t    = threadIdx.x;
    const int lane = t & 63;
    const int wv   = t >> 6;            // wave in WG: 0..3
    const int wid  = g * 4 + wv;        // global wave: 0..1023
    const int r0   = wid * 2;           // this wave's 2 rows

    // ---- W into registers: 2 rows; lane owns cols c*256 + lane*4..+3, c=0..7 ----
    v4 wreg[2][8];
    #pragma unroll
    for (int i = 0; i < 2; ++i)
        #pragma unroll
        for (int c = 0; c < 8; ++c)
            wreg[i][c] = *(const v4*)(W + (size_t)(r0 + i) * RSIZE + c * 256 + lane * 4);

    // ---- lanes 0,1 keep Win/Wfb for their row ----
    float win[N_IN] = {0}, wfb[N_OUT] = {0};
    if (lane < 2) {
        const int r = r0 + lane;
        #pragma unroll
        for (int j = 0; j < N_IN; ++j)  win[j] = Win[r * N_IN + j];
        #pragma unroll
        for (int k = 0; k < N_OUT; ++k) wfb[k] = Wfb[r * N_OUT + k];
    }

    // parity double-buffered x in LDS; xsh[p][i] = cols 4i..4i+3 (lane-contiguous)
    __shared__ v4 xsh[2][RSIZE / 4];    // 16 KB
    const int fi0 = wv * 128 + lane;         // wave fills cols [wv*512, wv*512+512)
    const int fi1 = wv * 128 + 64 + lane;

    // ---- prologue: stream terms for step n=1 (one-time full-latency load) ----
    float cur_pre = 0.0f, cur_nz = 0.0f;
    if (lane < 2) {
        const int r = r0 + lane;
        cur_nz = noise[(size_t)RSIZE + r];
        v4 i0 = *(const v4*)(inputs + N_IN);
        v4 i1 = *(const v4*)(inputs + N_IN + 4);
        v4 o0 = *(const v4*)(outputs);
        float p = 0.0f;
        p = fmaf(win[0], i0.x, p); p = fmaf(win[1], i0.y, p);
        p = fmaf(win[2], i0.z, p); p = fmaf(win[3], i0.w, p);
        p = fmaf(win[4], i1.x, p); p = fmaf(win[5], i1.y, p);
        p = fmaf(win[6], i1.z, p); p = fmaf(win[7], i1.w, p);
        p = fmaf(wfb[0], o0.x, p); p = fmaf(wfb[1], o0.y, p);
        p = fmaf(wfb[2], o0.z, p); p = fmaf(wfb[3], o0.w, p);
        cur_pre = p;
    }

    for (int n = 1; n < T_STEPS; ++n) {
        // ---- predicated poll: lane reads its two 16B chunks until non-sentinel ----
        const volatile v4* base =
            (const volatile v4*)(states + (size_t)(n - 1) * RSIZE);
        v4 a = {0.f, 0.f, 0.f, 0.f}, b = {0.f, 0.f, 0.f, 0.f};
        bool done = false;
        for (;;) {
            if (!done) {
                a = base[fi0];
                b = base[fi1];
                done = (__float_as_uint(a.x) != SENTINEL) &
                       (__float_as_uint(a.y) != SENTINEL) &
                       (__float_as_uint(a.z) != SENTINEL) &
                       (__float_as_uint(a.w) != SENTINEL) &
                       (__float_as_uint(b.x) != SENTINEL) &
                       (__float_as_uint(b.y) != SENTINEL) &
                       (__float_as_uint(b.z) != SENTINEL) &
                       (__float_as_uint(b.w) != SENTINEL);
            }
            if (__all(done)) break;
            __builtin_amdgcn_s_sleep(1);
        }

        // ---- issue NEXT step's stream loads now; they land during compute ----
        const bool hn = (n + 1 < T_STEPS);
        v4 ni0 = {0.f,0.f,0.f,0.f}, ni1 = {0.f,0.f,0.f,0.f}, no0 = {0.f,0.f,0.f,0.f};
        float nnz = 0.0f;
        if (lane < 2 && hn) {
            ni0 = *(const v4*)(inputs + (size_t)(n + 1) * N_IN);
            ni1 = *(const v4*)(inputs + (size_t)(n + 1) * N_IN + 4);
            no0 = *(const v4*)(outputs + (size_t)n * N_OUT);
            nnz = noise[(size_t)(n + 1) * RSIZE + r0 + lane];
        }

        const int p = (n - 1) & 1;
        xsh[p][fi0] = a;
        xsh[p][fi1] = b;
        __syncthreads();

        // ---- 2-row dot over 2048 cols from LDS (conflict-free), 4-way ILP ----
        float a0 = 0.f, a1 = 0.f, b0 = 0.f, b1 = 0.f;
        #pragma unroll
        for (int c = 0; c < 4; ++c) {
            v4 x0 = xsh[p][c * 64 + lane];
            v4 x1 = xsh[p][(c + 4) * 64 + lane];
            a0 += dot4(wreg[0][c], x0);
            b0 += dot4(wreg[0][c + 4], x1);
            a1 += dot4(wreg[1][c], x0);
            b1 += dot4(wreg[1][c + 4], x1);
        }
        float acc0 = a0 + b0;
        float acc1 = a1 + b1;

        // ---- fold reduction: 6 shfls; lane l<2 ends with row r0+l total ----
        float mine  = (lane & 1) ? acc1 : acc0;
        float other = (lane & 1) ? acc0 : acc1;
        mine += __shfl_xor(other, 1, 64);
        mine += __shfl_xor(mine, 2, 64);
        mine += __shfl_xor(mine, 4, 64);
        mine += __shfl_xor(mine, 8, 64);
        mine += __shfl_xor(mine, 16, 64);
        mine += __shfl_xor(mine, 32, 64);

        // ---- epilogue + publish (lanes 0,1 -> rows r0,r0+1, 8B coalesced) ----
        if (lane < 2) {
            float xn = tanhf(mine + cur_pre) + cur_nz;
            *(volatile float*)(states + (size_t)n * RSIZE + r0 + lane) = xn;
        }

        // ---- fold prefetched streams into (cur_pre, cur_nz) for next step ----
        if (lane < 2 && hn) {
            float pnext = 0.0f;
            pnext = fmaf(win[0], ni0.x, pnext); pnext = fmaf(win[1], ni0.y, pnext);
            pnext = fmaf(win[2], ni0.z, pnext); pnext = fmaf(win[3], ni0.w, pnext);
            pnext = fmaf(win[4], ni1.x, pnext); pnext = fmaf(win[5], ni1.y, pnext);
            pnext = fmaf(win[6], ni1.z, pnext); pnext = fmaf(win[7], ni1.w, pnext);
            pnext = fmaf(wfb[0], no0.x, pnext); pnext = fmaf(wfb[1], no0.y, pnext);
            pnext = fmaf(wfb[2], no0.z, pnext); pnext = fmaf(wfb[3], no0.w, pnext);
            cur_pre = pnext;
            cur_nz  = nnz;
        }
    }
}

__global__ __launch_bounds__(256) void readout_kernel(
    const float* __restrict__ states,   // [T][R]
    const float* __restrict__ inputs,   // [T][8]
    const float* __restrict__ lin_w,    // [4][2056]
    const float* __restrict__ lin_b,    // [4]
    float* __restrict__ out)            // [T][4]
{
    const int ti   = blockIdx.x;
    const int tid  = threadIdx.x;
    const int lane = tid & 63;
    const int wave = tid >> 6;
    const int c0   = tid * 8;

    const float* xp = states + (size_t)ti * RSIZE + c0;
    v4 xa = *(const v4*)xp;
    v4 xb = *(const v4*)(xp + 4);

    float acc[N_OUT];
    #pragma unroll
    for (int o = 0; o < N_OUT; ++o) {
        const float* lp = lin_w + (size_t)o * LIN_STRIDE + c0;
        v4 la = *(const v4*)lp;
        v4 lb = *(const v4*)(lp + 4);
        acc[o] = dot4(la, xa) + dot4(lb, xb);
    }

    #pragma unroll
    for (int m = 1; m < 64; m <<= 1) {
        #pragma unroll
        for (int o = 0; o < N_OUT; ++o) acc[o] += __shfl_xor(acc[o], m, 64);
    }

    __shared__ float red[4][N_OUT];
    if (lane == 0) {
        #pragma unroll
        for (int o = 0; o < N_OUT; ++o) red[wave][o] = acc[o];
    }
    __syncthreads();

    if (tid < N_OUT) {
        float s = red[0][tid] + red[1][tid] + red[2][tid] + red[3][tid] + lin_b[tid];
        if (ti > 0) {   // states_u row 0 is zero
            #pragma unroll
            for (int j = 0; j < N_IN; ++j)
                s = fmaf(lin_w[(size_t)tid * LIN_STRIDE + RSIZE + j],
                         inputs[ti * N_IN + j], s);
        }
        out[ti * N_OUT + tid] = s;
    }
}

extern "C" void kernel_launch(void* const* d_in, const int* in_sizes, int n_in,
                              void* d_out, int out_size, void* d_ws, size_t ws_size,
                              hipStream_t stream) {
    const float* inputs  = (const float*)d_in[0];
    const float* outputs = (const float*)d_in[1];
    const float* W       = (const float*)d_in[2];
    const float* Win     = (const float*)d_in[3];
    const float* Wfb     = (const float*)d_in[4];
    const float* lin_w   = (const float*)d_in[5];
    const float* lin_b   = (const float*)d_in[6];
    const float* noise   = (const float*)d_in[7];
    float* out = (float*)d_out;

    float* states = (float*)d_ws;

    hipLaunchKernelGGL(init_kernel, dim3((T_STEPS * RSIZE / 4) / 256), dim3(256), 0,
                       stream, (v4*)states);
    hipLaunchKernelGGL(reservoir_kernel, dim3(NWG), dim3(NT), 0, stream,
                       W, Win, Wfb, inputs, outputs, noise, states);
    hipLaunchKernelGGL(readout_kernel, dim3(T_STEPS), dim3(256), 0, stream,
                       states, inputs, lin_w, lin_b, out);
}

// Round 7
// 8104.319 us; speedup vs baseline: 1.3907x; 1.3907x over previous
//
#include <hip/hip_runtime.h>

#define T_STEPS 4096
#define RSIZE   2048
#define N_IN    8
#define N_OUT   4
#define NWG     256                  // 256 WGs x 4 waves = 1024 waves x 2 rows = 2048
#define NT      256
#define LIN_STRIDE  (RSIZE + N_IN)   // 2056 — readout weight row stride
#define SENTINEL    0x7FC00000u      // qNaN bits; recurrence never produces it

typedef float v4 __attribute__((ext_vector_type(4)));

// d_ws: states [T][R] float. Row 0 zeros, rows 1.. sentinel. Data IS the flag.

__global__ __launch_bounds__(256) void init_kernel(v4* __restrict__ states4) {
    int idx = blockIdx.x * 256 + threadIdx.x;        // 0 .. T*R/4-1
    const float s = __uint_as_float(SENTINEL);
    v4 v = (idx < RSIZE / 4) ? (v4){0.f, 0.f, 0.f, 0.f} : (v4){s, s, s, s};
    states4[idx] = v;
}

__device__ __forceinline__ float dot4(v4 a, v4 b) {
    float s = a.x * b.x;
    s = fmaf(a.y, b.y, s);
    s = fmaf(a.z, b.z, s);
    s = fmaf(a.w, b.w, s);
    return s;
}

__global__ __launch_bounds__(NT, 1) void reservoir_kernel(
    const float* __restrict__ W,        // [R][R]
    const float* __restrict__ Win,      // [R][8]
    const float* __restrict__ Wfb,      // [R][4]
    const float* __restrict__ inputs,   // [T][8]
    const float* __restrict__ outputs,  // [T][4]
    const float* __restrict__ noise,    // [T][R]
    float* __restrict__ states)         // [T][R]
{
    const int g    = blockIdx.x;
    const int t    = threadIdx.x;
    const int lane = t & 63;
    const int wv   = t >> 6;            // wave in WG: 0..3
    const int wid  = g * 4 + wv;        // global wave: 0..1023
    const int r0   = wid * 2;           // this wave's 2 rows

    // ---- W into registers: 2 rows; lane owns cols c*256 + lane*4..+3, c=0..7 ----
    v4 wreg[2][8];
    #pragma unroll
    for (int i = 0; i < 2; ++i)
        #pragma unroll
        for (int c = 0; c < 8; ++c)
            wreg[i][c] = *(const v4*)(W + (size_t)(r0 + i) * RSIZE + c * 256 + lane * 4);

    // ---- lanes 0,1 keep Win/Wfb for their row ----
    float win[N_IN] = {0}, wfb[N_OUT] = {0};
    if (lane < 2) {
        const int r = r0 + lane;
        #pragma unroll
        for (int j = 0; j < N_IN; ++j)  win[j] = Win[r * N_IN + j];
        #pragma unroll
        for (int k = 0; k < N_OUT; ++k) wfb[k] = Wfb[r * N_OUT + k];
    }

    // parity double-buffered x in LDS; xsh[p][i] = cols 4i..4i+3 (lane-contiguous)
    __shared__ v4 xsh[2][RSIZE / 4];    // 16 KB
    const int fi0 = wv * 128 + lane;         // wave fills cols [wv*512, wv*512+512)
    const int fi1 = wv * 128 + 64 + lane;

    // ---- prologue: stream terms for step n=1 (one-time full-latency load) ----
    float cur_pre = 0.0f, cur_nz = 0.0f;
    if (lane < 2) {
        const int r = r0 + lane;
        cur_nz = noise[(size_t)RSIZE + r];
        v4 i0 = *(const v4*)(inputs + N_IN);
        v4 i1 = *(const v4*)(inputs + N_IN + 4);
        v4 o0 = *(const v4*)(outputs);
        float p = 0.0f;
        p = fmaf(win[0], i0.x, p); p = fmaf(win[1], i0.y, p);
        p = fmaf(win[2], i0.z, p); p = fmaf(win[3], i0.w, p);
        p = fmaf(win[4], i1.x, p); p = fmaf(win[5], i1.y, p);
        p = fmaf(win[6], i1.z, p); p = fmaf(win[7], i1.w, p);
        p = fmaf(wfb[0], o0.x, p); p = fmaf(wfb[1], o0.y, p);
        p = fmaf(wfb[2], o0.z, p); p = fmaf(wfb[3], o0.w, p);
        cur_pre = p;
    }

    for (int n = 1; n < T_STEPS; ++n) {
        // ---- A: issue NEXT step's stream loads BEFORE the poll. They drain
        // during the poll wait (idle time) — never at the post-poll barrier. ----
        const bool hn = (n + 1 < T_STEPS);
        v4 ni0 = {0.f,0.f,0.f,0.f}, ni1 = {0.f,0.f,0.f,0.f}, no0 = {0.f,0.f,0.f,0.f};
        float nnz = 0.0f;
        if (lane < 2 && hn) {
            ni0 = *(const v4*)(inputs + (size_t)(n + 1) * N_IN);
            ni1 = *(const v4*)(inputs + (size_t)(n + 1) * N_IN + 4);
            no0 = *(const v4*)(outputs + (size_t)n * N_OUT);
            nnz = noise[(size_t)(n + 1) * RSIZE + r0 + lane];
        }

        // ---- B: predicated poll on my two 16B chunks of x_{n-1} ----
        const volatile v4* base =
            (const volatile v4*)(states + (size_t)(n - 1) * RSIZE);
        v4 a = {0.f, 0.f, 0.f, 0.f}, b = {0.f, 0.f, 0.f, 0.f};
        bool done = false;
        for (;;) {
            if (!done) {
                a = base[fi0];
                b = base[fi1];
                done = (__float_as_uint(a.x) != SENTINEL) &
                       (__float_as_uint(a.y) != SENTINEL) &
                       (__float_as_uint(a.z) != SENTINEL) &
                       (__float_as_uint(a.w) != SENTINEL) &
                       (__float_as_uint(b.x) != SENTINEL) &
                       (__float_as_uint(b.y) != SENTINEL) &
                       (__float_as_uint(b.z) != SENTINEL) &
                       (__float_as_uint(b.w) != SENTINEL);
            }
            if (__all(done)) break;
            __builtin_amdgcn_s_sleep(1);
        }

        // ---- C: share x via LDS (conflict-free lane-contiguous b128) ----
        const int p = (n - 1) & 1;
        xsh[p][fi0] = a;
        xsh[p][fi1] = b;
        __syncthreads();   // drains nothing but LDS: streams+store already drained in B

        // ---- D: 2-row dot over 2048 cols from LDS, 4-way ILP ----
        float a0 = 0.f, a1 = 0.f, b0 = 0.f, b1 = 0.f;
        #pragma unroll
        for (int c = 0; c < 4; ++c) {
            v4 x0 = xsh[p][c * 64 + lane];
            v4 x1 = xsh[p][(c + 4) * 64 + lane];
            a0 += dot4(wreg[0][c], x0);
            b0 += dot4(wreg[0][c + 4], x1);
            a1 += dot4(wreg[1][c], x0);
            b1 += dot4(wreg[1][c + 4], x1);
        }
        float acc0 = a0 + b0;
        float acc1 = a1 + b1;

        // ---- fold reduction: 6 shfls; lane l<2 ends with row r0+l total ----
        float mine  = (lane & 1) ? acc1 : acc0;
        float other = (lane & 1) ? acc0 : acc1;
        mine += __shfl_xor(other, 1, 64);
        mine += __shfl_xor(mine, 2, 64);
        mine += __shfl_xor(mine, 4, 64);
        mine += __shfl_xor(mine, 8, 64);
        mine += __shfl_xor(mine, 16, 64);
        mine += __shfl_xor(mine, 32, 64);

        // ---- E: epilogue + publish (lanes 0,1 -> rows r0,r0+1, 8B coalesced) ----
        if (lane < 2) {
            float xn = tanhf(mine + cur_pre) + cur_nz;
            *(volatile float*)(states + (size_t)n * RSIZE + r0 + lane) = xn;
        }

        // ---- F: fold prefetched streams (landed long ago) for next step ----
        if (lane < 2 && hn) {
            float pnext = 0.0f;
            pnext = fmaf(win[0], ni0.x, pnext); pnext = fmaf(win[1], ni0.y, pnext);
            pnext = fmaf(win[2], ni0.z, pnext); pnext = fmaf(win[3], ni0.w, pnext);
            pnext = fmaf(win[4], ni1.x, pnext); pnext = fmaf(win[5], ni1.y, pnext);
            pnext = fmaf(win[6], ni1.z, pnext); pnext = fmaf(win[7], ni1.w, pnext);
            pnext = fmaf(wfb[0], no0.x, pnext); pnext = fmaf(wfb[1], no0.y, pnext);
            pnext = fmaf(wfb[2], no0.z, pnext); pnext = fmaf(wfb[3], no0.w, pnext);
            cur_pre = pnext;
            cur_nz  = nnz;
        }
    }
}

__global__ __launch_bounds__(256) void readout_kernel(
    const float* __restrict__ states,   // [T][R]
    const float* __restrict__ inputs,   // [T][8]
    const float* __restrict__ lin_w,    // [4][2056]
    const float* __restrict__ lin_b,    // [4]
    float* __restrict__ out)            // [T][4]
{
    const int ti   = blockIdx.x;
    const int tid  = threadIdx.x;
    const int lane = tid & 63;
    const int wave = tid >> 6;
    const int c0   = tid * 8;

    const float* xp = states + (size_t)ti * RSIZE + c0;
    v4 xa = *(const v4*)xp;
    v4 xb = *(const v4*)(xp + 4);

    float acc[N_OUT];
    #pragma unroll
    for (int o = 0; o < N_OUT; ++o) {
        const float* lp = lin_w + (size_t)o * LIN_STRIDE + c0;
        v4 la = *(const v4*)lp;
        v4 lb = *(const v4*)(lp + 4);
        acc[o] = dot4(la, xa) + dot4(lb, xb);
    }

    #pragma unroll
    for (int m = 1; m < 64; m <<= 1) {
        #pragma unroll
        for (int o = 0; o < N_OUT; ++o) acc[o] += __shfl_xor(acc[o], m, 64);
    }

    __shared__ float red[4][N_OUT];
    if (lane == 0) {
        #pragma unroll
        for (int o = 0; o < N_OUT; ++o) red[wave][o] = acc[o];
    }
    __syncthreads();

    if (tid < N_OUT) {
        float s = red[0][tid] + red[1][tid] + red[2][tid] + red[3][tid] + lin_b[tid];
        if (ti > 0) {   // states_u row 0 is zero
            #pragma unroll
            for (int j = 0; j < N_IN; ++j)
                s = fmaf(lin_w[(size_t)tid * LIN_STRIDE + RSIZE + j],
                         inputs[ti * N_IN + j], s);
        }
        out[ti * N_OUT + tid] = s;
    }
}

extern "C" void kernel_launch(void* const* d_in, const int* in_sizes, int n_in,
                              void* d_out, int out_size, void* d_ws, size_t ws_size,
                              hipStream_t stream) {
    const float* inputs  = (const float*)d_in[0];
    const float* outputs = (const float*)d_in[1];
    const float* W       = (const float*)d_in[2];
    const float* Win     = (const float*)d_in[3];
    const float* Wfb     = (const float*)d_in[4];
    const float* lin_w   = (const float*)d_in[5];
    const float* lin_b   = (const float*)d_in[6];
    const float* noise   = (const float*)d_in[7];
    float* out = (float*)d_out;

    float* states = (float*)d_ws;

    hipLaunchKernelGGL(init_kernel, dim3((T_STEPS * RSIZE / 4) / 256), dim3(256), 0,
                       stream, (v4*)states);
    hipLaunchKernelGGL(reservoir_kernel, dim3(NWG), dim3(NT), 0, stream,
                       W, Win, Wfb, inputs, outputs, noise, states);
    hipLaunchKernelGGL(readout_kernel, dim3(T_STEPS), dim3(256), 0, stream,
                       states, inputs, lin_w, lin_b, out);
}